// Round 13
// baseline (166.058 us; speedup 1.0000x reference)
//
#include <hip/hip_runtime.h>

typedef short short8 __attribute__((ext_vector_type(8)));
typedef float f32x4 __attribute__((ext_vector_type(4)));
typedef unsigned int uint4v __attribute__((ext_vector_type(4)));

#define EPS_NUMER_F 1e-8f
#define EPS_D2_F 1e-12f

#define BB 128
#define TT 128
#define DD 1024
#define CHW 3072
#define NC 10
#define MM (BB * TT)
#define NT 48              // CHW / 64 K-tiles

#define GLOAD_LDS16(g, l)                                              \
  __builtin_amdgcn_global_load_lds(                                    \
      (const __attribute__((address_space(1))) void*)(g),              \
      (__attribute__((address_space(3))) void*)(l), 16, 0, 0)

#define DS_READ_B128(dst_, off_) \
  asm volatile("ds_read_b128 %0, %1" : "=v"(dst_) : "v"(off_))
#define DS_WRITE_B128(off_, val_) \
  asm volatile("ds_write_b128 %0, %1" :: "v"(off_), "v"(val_))
#define GLB_LOAD_X4(dst_, voff_, imm_) \
  asm volatile("global_load_dwordx4 %0, %1, %2 offset:" #imm_ \
               : "=v"(dst_) : "v"(voff_), "s"(xbase))
#define SCHED_FENCE() __builtin_amdgcn_sched_barrier(0)

static __device__ __forceinline__ unsigned lds_addr(const void* p) {
  return (unsigned)(unsigned long long)(const __attribute__((address_space(3))) void*)p;
}
static __device__ __forceinline__ unsigned cvt2(float lo, float hi) {
  unsigned r;
  asm("v_cvt_pk_bf16_f32 %0, %1, %2" : "=v"(r) : "v"(lo), "v"(hi));
  return r;
}

static __device__ __forceinline__ short f2bf(float x) {
  unsigned int u = __float_as_uint(x);
  u = (u + 0x7fffu + ((u >> 16) & 1u)) >> 16;
  return (short)u;
}
static __device__ __forceinline__ float bf2f(short x) {
  return __uint_as_float(((unsigned int)(unsigned short)x) << 16);
}

// ---------------------------------------------------------------------------
// W_fe (3072 x 1024 f32, K x N) -> Wt (1024 x 3072 bf16, N x K)
// ---------------------------------------------------------------------------
__global__ __launch_bounds__(256) void k_transpose_w(const float* __restrict__ W,
                                                     short* __restrict__ Wt) {
  __shared__ float tile[32][33];
  const int n0 = blockIdx.x * 32;
  const int k0 = blockIdx.y * 32;
  const int tx = threadIdx.x & 31;
  const int ty = threadIdx.x >> 5;
#pragma unroll
  for (int i = 0; i < 32; i += 8)
    tile[ty + i][tx] = W[(size_t)(k0 + ty + i) * DD + (n0 + tx)];
  __syncthreads();
#pragma unroll
  for (int i = 0; i < 32; i += 8)
    Wt[(size_t)(n0 + ty + i) * CHW + (k0 + tx)] = f2bf(tile[tx][ty + i]);
}

// ---------------------------------------------------------------------------
// Fused 256x256 GEMM, ONE barrier per K-tile: F = bf16(X) @ Wt^T + b.
// Within a tile, per-wave software pipeline: read chunk i+1 issued BEFORE
// MFMA cluster i, counted lgkmcnt between -> LDS pipe overlaps matrix pipe.
// Buffer-parity hazard handled by the single loop-top barrier; all staging
// drained (lgkm(0)+vmcnt(0), both ~free) before it.
// ---------------------------------------------------------------------------
__global__ __launch_bounds__(512, 2) void k_gemm_1b(const float* __restrict__ X,
                                                    const short* __restrict__ Wt,
                                                    const float* __restrict__ bias,
                                                    short* __restrict__ F) {
  __shared__ short As[2][256 * 64];
  __shared__ short Bs[2][256 * 64];

  const int bid = blockIdx.x;
  const int id = (bid & 7) * 32 + (bid >> 3);
  const int bm = (id >> 2) << 8;
  const int bn = (id & 3) << 8;

  const int tid = threadIdx.x;
  const int lane = tid & 63;
  const int wid = tid >> 6;
  const int wr = wid >> 2;
  const int wc = wid & 3;

  // ---- B staging (gload_lds, pre-swizzled source)
  const int srow = lane >> 3;
  const int sslot = (lane & 7) ^ (lane >> 3);
  const short* bSrc = Wt + (size_t)(bn + srow) * CHW + sslot * 8;

#define STAGE_B_HALF(T_, h_) do {                                            \
    int base_ = (h_) * 128 + wid * 8;                                        \
    GLOAD_LDS16(bSrc + (size_t)(base_) * CHW + (T_) * 64,                    \
                &Bs[(T_) & 1][(base_) * 64]);                                \
    GLOAD_LDS16(bSrc + (size_t)(base_ + 64) * CHW + (T_) * 64,              \
                &Bs[(T_) & 1][(base_ + 64) * 64]);                           \
  } while (0)

  // ---- A staging: asm global loads (vmcnt-only) + cvt_pk + swizzled ds_write
  const int arow_st = wid * 16 + (lane >> 3);
  const unsigned long long xbase = (unsigned long long)X;
  unsigned voff[4];
#pragma unroll
  for (int h = 0; h < 2; ++h)
#pragma unroll
    for (int j = 0; j < 2; ++j)
      voff[h * 2 + j] = (unsigned)(((bm + h * 128 + j * 8 + arow_st) * (size_t)CHW
                                    + (lane & 7) * 8) * 4);
  const unsigned aposb = (unsigned)(((lane & 7) ^ (lane >> 3)) * 16);

  f32x4 ra[4], rb[4];

#define LOAD_A_H0() do {                                                     \
    GLB_LOAD_X4(ra[0], voff[0], 0);  GLB_LOAD_X4(ra[1], voff[0], 16);        \
    GLB_LOAD_X4(ra[2], voff[1], 0);  GLB_LOAD_X4(ra[3], voff[1], 16);        \
  } while (0)
#define LOAD_A_H1() do {                                                     \
    GLB_LOAD_X4(rb[0], voff[2], 0);  GLB_LOAD_X4(rb[1], voff[2], 16);        \
    GLB_LOAD_X4(rb[2], voff[3], 0);  GLB_LOAD_X4(rb[3], voff[3], 16);        \
  } while (0)
#define ADV_A() do { voff[0] += 256; voff[1] += 256; voff[2] += 256; voff[3] += 256; } while (0)
#define WRITE_A_HALF(T_, h_, d_) do {                                        \
    unsigned ad_ = aWrBase + (((T_) & 1) ? 32768u : 0u) + (h_) * 16384u;     \
    uint4v w0_, w1_;                                                         \
    w0_.x = cvt2(d_[0].x, d_[0].y); w0_.y = cvt2(d_[0].z, d_[0].w);          \
    w0_.z = cvt2(d_[1].x, d_[1].y); w0_.w = cvt2(d_[1].z, d_[1].w);          \
    DS_WRITE_B128(ad_, w0_);                                                 \
    w1_.x = cvt2(d_[2].x, d_[2].y); w1_.y = cvt2(d_[2].z, d_[2].w);          \
    w1_.z = cvt2(d_[3].x, d_[3].y); w1_.w = cvt2(d_[3].z, d_[3].w);          \
    DS_WRITE_B128(ad_ + 1024u, w1_);                                         \
  } while (0)

  // fragment read addressing (swizzled)
  const int fr = lane & 15;
  const int sl = lane >> 4;
  const int slotk0 = (0 + sl) ^ (lane & 7);
  const int slotk1 = (4 + sl) ^ (lane & 7);
  const int arow = wr * 128 + fr;
  const int brow = wc * 64 + fr;

  const unsigned aBase0 = lds_addr(&As[0][0]);
  const unsigned bBase0 = lds_addr(&Bs[0][0]);
  const unsigned aWrBase = aBase0 + (unsigned)(arow_st * 128) + aposb;

  short8 bf_[8];         // all B frags for current tile
  short8 aqE[4], aqO[4]; // A-quad ping-pong: E = quads 0,2; O = quads 1,3
  f32x4 acc[8][4] = {};

// read B pair ni (both k-slots) into bf_[2ni..2ni+1]
#define READ_B_PAIR(ni_, bb_) do {                                           \
    DS_READ_B128(bf_[(ni_) * 2 + 0], (bb_) + (unsigned)((brow + (ni_) * 16) * 128 + slotk0 * 16)); \
    DS_READ_B128(bf_[(ni_) * 2 + 1], (bb_) + (unsigned)((brow + (ni_) * 16) * 128 + slotk1 * 16)); \
  } while (0)
#define READ_AQ(set_, q_, ab_) do {                                          \
    DS_READ_B128(set_[0], (ab_) + (unsigned)((arow + (2*(q_))    *16)*128 + slotk0*16)); \
    DS_READ_B128(set_[1], (ab_) + (unsigned)((arow + (2*(q_))    *16)*128 + slotk1*16)); \
    DS_READ_B128(set_[2], (ab_) + (unsigned)((arow + (2*(q_) + 1)*16)*128 + slotk0*16)); \
    DS_READ_B128(set_[3], (ab_) + (unsigned)((arow + (2*(q_) + 1)*16)*128 + slotk1*16)); \
  } while (0)
// MFMA: quad q_ (register set set_) x B pairs [nlo_, nhi_)
#define MFMA_Q(q_, set_, nlo_, nhi_) do {                                    \
    _Pragma("unroll")                                                        \
    for (int m2 = 0; m2 < 2; ++m2)                                           \
      _Pragma("unroll")                                                      \
      for (int ks = 0; ks < 2; ++ks)                                         \
        _Pragma("unroll")                                                    \
        for (int ni = (nlo_); ni < (nhi_); ++ni)                             \
          acc[2*(q_)+m2][ni] = __builtin_amdgcn_mfma_f32_16x16x32_bf16(      \
              set_[m2*2+ks], bf_[ni*2+ks], acc[2*(q_)+m2][ni], 0, 0, 0);     \
  } while (0)

  // ---- prologue: stage tile 0 only.  A(0):8 glb, B(0):4 gload_lds;
  // vmcnt(4) drains A(0) (leaves B(0)); write A(0); drain all; -> loop barrier.
  LOAD_A_H0();
  LOAD_A_H1();
  STAGE_B_HALF(0, 0); STAGE_B_HALF(0, 1);
  SCHED_FENCE();
  asm volatile("s_waitcnt vmcnt(4)");
  SCHED_FENCE();
  WRITE_A_HALF(0, 0, ra);
  WRITE_A_HALF(0, 1, rb);
  ADV_A();                                 // voff -> tile 1
  asm volatile("s_waitcnt vmcnt(0)");      // B(0) landed
  asm volatile("s_waitcnt lgkmcnt(0)");    // A(0) writes done
  SCHED_FENCE();

  for (int T = 0; T < NT; ++T) {
    const unsigned ab = aBase0 + ((T & 1) ? 32768u : 0u);
    const unsigned bb = bBase0 + ((T & 1) ? 32768u : 0u);

    // single per-tile barrier: all waves done reading buf (tile T-2 parity)
    // and all staging for tile T drained -> buf' free, buf valid.
    __builtin_amdgcn_s_barrier();

    // issue tile T+1 VMEM: A first (drained mid-tile), then B (verified at end)
    if (T + 1 < NT) {
      LOAD_A_H0();
      LOAD_A_H1();
      ADV_A();
      STAGE_B_HALF(T + 1, 0);
      STAGE_B_HALF(T + 1, 1);
    }

    // R0: B pairs 0,1 + A quad 0 (8 reads);  R1: B pairs 2,3 + A quad 1 (8)
    READ_B_PAIR(0, bb); READ_B_PAIR(1, bb);
    READ_AQ(aqE, 0, ab);
    READ_B_PAIR(2, bb); READ_B_PAIR(3, bb);
    READ_AQ(aqO, 1, ab);
    SCHED_FENCE();
    asm volatile("s_waitcnt lgkmcnt(8)");   // R0 done, R1 in flight
    SCHED_FENCE();
    __builtin_amdgcn_s_setprio(1);
    MFMA_Q(0, aqE, 0, 2);                   // C0: 8 MFMA (under R1 drain)
    __builtin_amdgcn_s_setprio(0);
    SCHED_FENCE();
    asm volatile("s_waitcnt lgkmcnt(0)");   // R1 done
    SCHED_FENCE();
    __builtin_amdgcn_s_setprio(1);
    MFMA_Q(0, aqE, 2, 4);                   // C1a: 8 (last use of old aqE)
    __builtin_amdgcn_s_setprio(0);
    SCHED_FENCE();
    READ_AQ(aqE, 2, ab);                    // R2: A quad 2 (4 reads)
    SCHED_FENCE();
    __builtin_amdgcn_s_setprio(1);
    MFMA_Q(1, aqO, 0, 4);                   // C1b: 16 (under R2 drain)
    __builtin_amdgcn_s_setprio(0);
    SCHED_FENCE();
    asm volatile("s_waitcnt lgkmcnt(0)");   // R2 done
    SCHED_FENCE();
    READ_AQ(aqO, 3, ab);                    // R3: A quad 3 (4 reads)
    SCHED_FENCE();
    __builtin_amdgcn_s_setprio(1);
    MFMA_Q(2, aqE, 0, 4);                   // C2: 16 (under R3 drain)
    __builtin_amdgcn_s_setprio(0);
    SCHED_FENCE();
    // mid-tile: drain A(T+1) globals (queue [A:8, B:4] -> vmcnt(4) = A done)
    if (T + 1 < NT) {
      asm volatile("s_waitcnt vmcnt(4)");
      SCHED_FENCE();
      WRITE_A_HALF(T + 1, 0, ra);
      WRITE_A_HALF(T + 1, 1, rb);
      SCHED_FENCE();
      asm volatile("s_waitcnt lgkmcnt(4)"); // drain R3, leave 4 ds_writes
    } else {
      asm volatile("s_waitcnt lgkmcnt(0)"); // tail: drain R3
    }
    SCHED_FENCE();
    __builtin_amdgcn_s_setprio(1);
    MFMA_Q(3, aqO, 0, 4);                   // C3: 16 (under A-write drain)
    __builtin_amdgcn_s_setprio(0);
    SCHED_FENCE();
    asm volatile("s_waitcnt lgkmcnt(0)");   // A writes done
    asm volatile("s_waitcnt vmcnt(0)");     // B(T+1) verified (issued ~tile ago)
    SCHED_FENCE();
  }

  // epilogue: C/D layout col = lane&15, row = (lane>>4)*4 + q
  const int cc = lane & 15;
  const int crr = sl << 2;
#pragma unroll
  for (int ni = 0; ni < 4; ++ni) {
    int col = bn + wc * 64 + ni * 16 + cc;
    float bv = bias[col];
#pragma unroll
    for (int mi = 0; mi < 8; ++mi) {
      int row0 = bm + wr * 128 + mi * 16 + crr;
#pragma unroll
      for (int q = 0; q < 4; ++q)
        F[(size_t)(row0 + q) * DD + col] = f2bf(acc[mi][ni][q] + bv);
    }
  }
#undef READ_B_PAIR
#undef READ_AQ
#undef MFMA_Q
#undef STAGE_B_HALF
#undef LOAD_A_H0
#undef LOAD_A_H1
#undef ADV_A
#undef WRITE_A_HALF
}

// ---------------------------------------------------------------------------
// Kernel 3: per (batch, t-half): Gram via MFMA -> d2 -> sims -> causal numer
// -> pow/normalize -> out.
// ---------------------------------------------------------------------------
__global__ __launch_bounds__(256) void k_batch_sims(const short* __restrict__ F,
                                                    const float* __restrict__ teach,
                                                    const float* __restrict__ cptr,
                                                    const float* __restrict__ gptr,
                                                    float* __restrict__ out) {
  __shared__ short ftile[128][40];
  __shared__ float simsT[64][129];
  __shared__ float sqv[128];
  __shared__ float sqp[256];
  __shared__ float teach_s[128][NC];
  __shared__ float numer[64][NC];
  __shared__ float rsum[64];

  const int b = blockIdx.x >> 1;
  const int half = blockIdx.x & 1;
  const int tid = threadIdx.x;
  const int lane = tid & 63;
  const int w = tid >> 6;
  const size_t fbase = (size_t)b * TT * DD;

  for (int idx = tid; idx < TT * NC; idx += 256)
    teach_s[idx / NC][idx % NC] = teach[(size_t)b * TT * NC + idx];

  {
    int row = tid >> 1;
    int kh = (tid & 1) << 9;
    const short* fp = F + fbase + (size_t)row * DD + kh;
    float s = 0.f;
    for (int k = 0; k < 512; k += 8) {
      short8 v = *reinterpret_cast<const short8*>(fp + k);
#pragma unroll
      for (int j = 0; j < 8; ++j) { float x = bf2f(v[j]); s += x * x; }
    }
    sqp[tid] = s;
  }
  __syncthreads();
  if (tid < 128) sqv[tid] = sqp[2 * tid] + sqp[2 * tid + 1];
  __syncthreads();

  f32x4 acc[2][4] = {};
  const int fr = lane & 15;
  const int fk = (lane >> 4) << 3;
  for (int k0 = 0; k0 < DD; k0 += 32) {
#pragma unroll
    for (int i = 0; i < 2; ++i) {
      int idx = tid + (i << 8);
      int row = idx >> 2;
      int kc = (idx & 3) << 3;
      short8 v = *reinterpret_cast<const short8*>(F + fbase + (size_t)row * DD + (k0 + kc));
      *reinterpret_cast<short8*>(&ftile[row][kc]) = v;
    }
    __syncthreads();
    short8 af[2], bfv[4];
#pragma unroll
    for (int mi = 0; mi < 2; ++mi)
      af[mi] = *reinterpret_cast<const short8*>(&ftile[w * 32 + mi * 16 + fr][fk]);
#pragma unroll
    for (int ni = 0; ni < 4; ++ni)
      bfv[ni] = *reinterpret_cast<const short8*>(&ftile[half * 64 + ni * 16 + fr][fk]);
#pragma unroll
    for (int mi = 0; mi < 2; ++mi)
#pragma unroll
      for (int ni = 0; ni < 4; ++ni)
        acc[mi][ni] = __builtin_amdgcn_mfma_f32_16x16x32_bf16(af[mi], bfv[ni], acc[mi][ni], 0, 0, 0);
    __syncthreads();
  }

  const float c0 = cptr[0];
  const int cc = lane & 15;
  const int crr = (lane >> 4) << 2;
#pragma unroll
  for (int mi = 0; mi < 2; ++mi) {
#pragma unroll
    for (int ni = 0; ni < 4; ++ni) {
#pragma unroll
      for (int q = 0; q < 4; ++q) {
        int s_g = w * 32 + mi * 16 + crr + q;
        int tl = ni * 16 + cc;
        int t_g = half * 64 + tl;
        float g = acc[mi][ni][q];
        float d2 = sqv[s_g] + sqv[t_g] - 2.0f * g;
        d2 = fmaxf(d2, EPS_D2_F);
        float dist = sqrtf(sqrtf(d2));
        simsT[tl][s_g] = (s_g < t_g) ? expf(-c0 * dist) : 0.0f;
      }
    }
  }
  __syncthreads();

  const float gam = gptr[0];
  for (int idx = tid; idx < 64 * NC; idx += 256) {
    int tl = idx / NC, c = idx % NC;
    float s = 0.f;
#pragma unroll 4
    for (int si = 0; si < TT; ++si)
      s += simsT[tl][si] * teach_s[si][c];
    float v = EPS_NUMER_F + s;
    numer[tl][c] = (gam == 1.0f) ? v : powf(v, gam);
  }
  __syncthreads();
  if (tid < 64) {
    float s = 0.f;
#pragma unroll
    for (int c = 0; c < NC; ++c) s += numer[tid][c];
    rsum[tid] = s;
  }
  __syncthreads();
  for (int idx = tid; idx < 64 * NC; idx += 256) {
    int tl = idx / NC, c = idx % NC;
    int t_g = half * 64 + tl;
    float v = numer[tl][c] / rsum[tl];
    if (t_g == 0) v = EPS_NUMER_F;
    out[(size_t)b * TT * NC + (size_t)t_g * NC + c] = v;
  }
}

// ---------------------------------------------------------------------------
extern "C" void kernel_launch(void* const* d_in, const int* in_sizes, int n_in,
                              void* d_out, int out_size, void* d_ws, size_t ws_size,
                              hipStream_t stream) {
  const float* data = (const float*)d_in[1];
  const float* teach = (const float*)d_in[2];
  const float* Wfe = (const float*)d_in[3];
  const float* bfe = (const float*)d_in[4];
  const float* cp = (const float*)d_in[5];
  const float* gp = (const float*)d_in[6];
  float* outp = (float*)d_out;

  char* ws = (char*)d_ws;
  short* Wt = (short*)ws;                             // @0:   6.29 MB
  short* F = (short*)(ws + (size_t)8 * 1024 * 1024);  // @8MB: 33.55 MB

  k_transpose_w<<<dim3(DD / 32, CHW / 32), 256, 0, stream>>>(Wfe, Wt);
  k_gemm_1b<<<dim3((MM / 256) * (DD / 256)), 512, 0, stream>>>(data, Wt, bfe, F);
  k_batch_sims<<<dim3(BB * 2), 256, 0, stream>>>(F, teach, cp, gp, outp);
}

// Round 15
// 131.137 us; speedup vs baseline: 1.2663x; 1.2663x over previous
//
#include <hip/hip_runtime.h>

typedef short short8 __attribute__((ext_vector_type(8)));
typedef float f32x4 __attribute__((ext_vector_type(4)));
typedef int int2v __attribute__((ext_vector_type(2)));
typedef int int4v __attribute__((ext_vector_type(4)));
typedef int int8v __attribute__((ext_vector_type(8)));

#define EPS_NUMER_F 1e-8f
#define EPS_D2_F 1e-12f

#define BB 128
#define TT 128
#define DD 1024
#define CHW 3072
#define NC 10
#define MM (BB * TT)
#define NT 24              // CHW / 128 K-tiles
#define WSCALE 64.0f
#define INV_WSCALE 0.015625f

#define GLOAD_LDS16(g, l)                                              \
  __builtin_amdgcn_global_load_lds(                                    \
      (const __attribute__((address_space(1))) void*)(g),              \
      (__attribute__((address_space(3))) void*)(l), 16, 0, 0)

#define DS_READ_B128(dst_, off_) \
  asm volatile("ds_read_b128 %0, %1" : "=v"(dst_) : "v"(off_))
#define DS_WRITE_B64(off_, val_) \
  asm volatile("ds_write_b64 %0, %1" :: "v"(off_), "v"(val_))
#define GLB_LOAD_X4(dst_, voff_, imm_) \
  asm volatile("global_load_dwordx4 %0, %1, %2 offset:" #imm_ \
               : "=v"(dst_) : "v"(voff_), "s"(xbase))
#define SCHED_FENCE() __builtin_amdgcn_sched_barrier(0)

#define UNIT_SCALE 0x7f7f7f7f   // E8M0 exponent 127 = 1.0 in every byte

static __device__ __forceinline__ unsigned lds_addr(const void* p) {
  return (unsigned)(unsigned long long)(const __attribute__((address_space(3))) void*)p;
}

static __device__ __forceinline__ short f2bf(float x) {
  unsigned int u = __float_as_uint(x);
  u = (u + 0x7fffu + ((u >> 16) & 1u)) >> 16;
  return (short)u;
}
static __device__ __forceinline__ float bf2f(short x) {
  return __uint_as_float(((unsigned int)(unsigned short)x) << 16);
}

// pack 8 f32 (two f32x4, consecutive k) -> 8 fp8 e4m3 bytes in an int2
static __device__ __forceinline__ int2v pk8_fp8(f32x4 a, f32x4 b) {
  int2v r;
  int w0 = __builtin_amdgcn_cvt_pk_fp8_f32(a.x, a.y, 0, false);
  w0 = __builtin_amdgcn_cvt_pk_fp8_f32(a.z, a.w, w0, true);
  int w1 = __builtin_amdgcn_cvt_pk_fp8_f32(b.x, b.y, 0, false);
  w1 = __builtin_amdgcn_cvt_pk_fp8_f32(b.z, b.w, w1, true);
  r.x = w0; r.y = w1;
  return r;
}

// ---------------------------------------------------------------------------
// W_fe (3072 x 1024 f32, K x N) -> Wt8 (1024 x 3072 fp8 e4m3, N x K), x64
// ---------------------------------------------------------------------------
__global__ __launch_bounds__(256) void k_transpose_w8(const float* __restrict__ W,
                                                      char* __restrict__ Wt8) {
  __shared__ float tile[32][33];
  const int n0 = blockIdx.x * 32;
  const int k0 = blockIdx.y * 32;
  const int tx = threadIdx.x & 31;
  const int ty = threadIdx.x >> 5;
#pragma unroll
  for (int i = 0; i < 32; i += 8)
    tile[ty + i][tx] = W[(size_t)(k0 + ty + i) * DD + (n0 + tx)];
  __syncthreads();
  const int n = threadIdx.x >> 3;
  const int kq = (threadIdx.x & 7) * 4;
  float a0 = tile[kq + 0][n] * WSCALE;
  float a1 = tile[kq + 1][n] * WSCALE;
  float a2 = tile[kq + 2][n] * WSCALE;
  float a3 = tile[kq + 3][n] * WSCALE;
  int w = __builtin_amdgcn_cvt_pk_fp8_f32(a0, a1, 0, false);
  w = __builtin_amdgcn_cvt_pk_fp8_f32(a2, a3, w, true);
  *reinterpret_cast<int*>(Wt8 + (size_t)(n0 + n) * CHW + (k0 + kq)) = w;
}

// ---------------------------------------------------------------------------
// Fused 256x256 MX-fp8 GEMM: F = bf16( (fp8(X) @ fp8(64*W)^T)/64 + b ).
// BK=128, NT=24, 512 thr (8 waves 2Mx4N), mfma_scale_f32_16x16x128_f8f6f4
// with unit scales.  r7's 4-phase skeleton + counted-vmcnt ledger.
// FIX vs r14: A kh1 ds_write slot is ((j+4) ^ row&7), NOT byte+64 —
// the +64 form overflowed the slot field for rows with (row&7)>=4.
// ---------------------------------------------------------------------------
__global__ __launch_bounds__(512, 2) void k_gemm_mx(const float* __restrict__ X,
                                                    const char* __restrict__ Wt8,
                                                    const float* __restrict__ bias,
                                                    short* __restrict__ F) {
  __shared__ char As[2][256 * 128];   // 32 KiB / buf
  __shared__ char Bs[2][256 * 128];

  const int bid = blockIdx.x;
  const int id = (bid & 7) * 32 + (bid >> 3);
  const int bm = (id >> 2) << 8;
  const int bn = (id & 3) << 8;

  const int tid = threadIdx.x;
  const int lane = tid & 63;
  const int wid = tid >> 6;
  const int wr = wid >> 2;         // 0..1 -> rows wr*128
  const int wc = wid & 3;          // 0..3 -> cols wc*64

  // ---- B staging (gload_lds, pre-swizzled source). Row = 128 B, 8 slots of
  // 16 B; lane: row += lane>>3, src slot (lane&7)^(lane>>3).
  const int srow = lane >> 3;
  const int sslot = (lane & 7) ^ (lane >> 3);
  const char* bSrc = Wt8 + (size_t)(bn + srow) * CHW + sslot * 16;

#define STAGE_B_HALF(T_, h_) do {                                            \
    int base_ = (h_) * 128 + wid * 8;                                        \
    GLOAD_LDS16(bSrc + (size_t)(base_) * CHW + (T_) * 128,                   \
                &Bs[(T_) & 1][(base_) * 128]);                               \
    GLOAD_LDS16(bSrc + (size_t)(base_ + 64) * CHW + (T_) * 128,             \
                &Bs[(T_) & 1][(base_ + 64) * 128]);                          \
  } while (0)

  // ---- A staging: thread covers 4 rows {h*128 + j*8 + arow_st}, 8 f32 at
  // k = kh*64 + (lane&7)*8.  cvt_pk_fp8 -> 8 B -> 1 ds_write_b64 per row.
  const int arow_st = wid * 16 + (lane >> 3);
  const unsigned long long xbase = (unsigned long long)X;
  unsigned voff[4];
#pragma unroll
  for (int h = 0; h < 2; ++h)
#pragma unroll
    for (int j = 0; j < 2; ++j)
      voff[h * 2 + j] = (unsigned)(((bm + h * 128 + j * 8 + arow_st) * (size_t)CHW
                                    + (lane & 7) * 8) * 4);

  f32x4 ra[8];   // 32 f32 in flight for one k-half

#define LOAD_A_KH0() do {                                                    \
    GLB_LOAD_X4(ra[0], voff[0], 0);   GLB_LOAD_X4(ra[1], voff[0], 16);       \
    GLB_LOAD_X4(ra[2], voff[1], 0);   GLB_LOAD_X4(ra[3], voff[1], 16);       \
    GLB_LOAD_X4(ra[4], voff[2], 0);   GLB_LOAD_X4(ra[5], voff[2], 16);       \
    GLB_LOAD_X4(ra[6], voff[3], 0);   GLB_LOAD_X4(ra[7], voff[3], 16);       \
  } while (0)
#define LOAD_A_KH1() do {                                                    \
    GLB_LOAD_X4(ra[0], voff[0], 256); GLB_LOAD_X4(ra[1], voff[0], 272);      \
    GLB_LOAD_X4(ra[2], voff[1], 256); GLB_LOAD_X4(ra[3], voff[1], 272);      \
    GLB_LOAD_X4(ra[4], voff[2], 256); GLB_LOAD_X4(ra[5], voff[2], 272);      \
    GLB_LOAD_X4(ra[6], voff[3], 256); GLB_LOAD_X4(ra[7], voff[3], 272);      \
  } while (0)
#define ADV_A() do { voff[0] += 512; voff[1] += 512; voff[2] += 512; voff[3] += 512; } while (0)

  // A LDS write addressing.  8-byte chunk c = lane&7 holds k-bytes
  // [kh*64 + c*8, +8) -> k-slot j = kh*4 + (c>>1), half (c&1).
  // Stored slot = j ^ (row&7), row&7 = lane>>3.  (FIX: slot math, not +64.)
  const int cA = lane & 7;
  const int r8A = lane >> 3;
  unsigned awr0[4], awr1[4];
#pragma unroll
  for (int hj = 0; hj < 4; ++hj) {
    int lrow = (hj >> 1) * 128 + (hj & 1) * 8 + arow_st;
    awr0[hj] = (unsigned)(lrow * 128 + (((cA >> 1)     ^ r8A) * 16) + (cA & 1) * 8);
    awr1[hj] = (unsigned)(lrow * 128 + ((((cA >> 1)+4) ^ r8A) * 16) + (cA & 1) * 8);
  }

#define WRITE_A_KH(T_, kh_) do {                                             \
    unsigned bo_ = (((T_) & 1) ? 32768u : 0u);                               \
    _Pragma("unroll")                                                        \
    for (int hj = 0; hj < 4; ++hj) {                                         \
      int2v w_ = pk8_fp8(ra[hj * 2], ra[hj * 2 + 1]);                        \
      DS_WRITE_B64(aWrBase + ((kh_) ? awr1[hj] : awr0[hj]) + bo_, w_);       \
    }                                                                        \
  } while (0)

  // fragment read addressing: frag = 32 B = 2 b128 at slots {2sl, 2sl+1} ^ (row&7)
  const int fr = lane & 15;
  const int sl = lane >> 4;          // k-block selector
  const unsigned fslot0 = (unsigned)((((sl * 2) ^ (fr & 7)) * 16));
  const int arow = wr * 128 + fr;
  const int brow = wc * 64 + fr;

  const unsigned aBase0 = lds_addr(&As[0][0]);
  const unsigned bBase0 = lds_addr(&Bs[0][0]);
  const unsigned aWrBase = aBase0;

  int4v bql[4], bqh[4];
  int4v aql[2], aqh[2];
  f32x4 acc[8][4] = {};

#define READ_B8(bb_) do {                                                    \
    _Pragma("unroll")                                                        \
    for (int ni = 0; ni < 4; ++ni) {                                         \
      unsigned ba_ = (bb_) + (unsigned)((brow + ni * 16) * 128) + fslot0;    \
      DS_READ_B128(bql[ni], ba_);                                            \
      DS_READ_B128(bqh[ni], ba_ ^ 16u);                                      \
    }                                                                        \
  } while (0)
#define READ_A_PAIR(p_, ab_) do {                                            \
    _Pragma("unroll")                                                        \
    for (int m2 = 0; m2 < 2; ++m2) {                                         \
      unsigned aa_ = (ab_) + (unsigned)((arow + (2 * (p_) + m2) * 16) * 128) + fslot0; \
      DS_READ_B128(aql[m2], aa_);                                            \
      DS_READ_B128(aqh[m2], aa_ ^ 16u);                                      \
    }                                                                        \
  } while (0)
#define MFMA8(p_) do {                                                       \
    _Pragma("unroll")                                                        \
    for (int m2 = 0; m2 < 2; ++m2) {                                         \
      int8v av_ = __builtin_shufflevector(aql[m2], aqh[m2], 0,1,2,3,4,5,6,7);\
      _Pragma("unroll")                                                      \
      for (int ni = 0; ni < 4; ++ni) {                                       \
        int8v bv_ = __builtin_shufflevector(bql[ni], bqh[ni], 0,1,2,3,4,5,6,7);\
        acc[2*(p_)+m2][ni] = __builtin_amdgcn_mfma_scale_f32_16x16x128_f8f6f4(\
            av_, bv_, acc[2*(p_)+m2][ni], 0, 0,                              \
            0, UNIT_SCALE, 0, UNIT_SCALE);                                   \
      }                                                                      \
    }                                                                        \
  } while (0)

  // ---- prologue: A(0)kh0:8, B(0):4 -> vmcnt(4) drains A; write kh0;
  // A(0)kh1:8, B(1):4 -> vmcnt(4) drains B(0)+kh1, leaves B(1); write kh1.
  LOAD_A_KH0();
  STAGE_B_HALF(0, 0); STAGE_B_HALF(0, 1);
  SCHED_FENCE();
  asm volatile("s_waitcnt vmcnt(4)");
  SCHED_FENCE();
  WRITE_A_KH(0, 0);
  LOAD_A_KH1();
  STAGE_B_HALF(1, 0); STAGE_B_HALF(1, 1);
  SCHED_FENCE();
  asm volatile("s_waitcnt vmcnt(4)");
  SCHED_FENCE();
  WRITE_A_KH(0, 1);
  ADV_A();                                 // voff -> tile 1
  asm volatile("s_waitcnt lgkmcnt(0)");
  SCHED_FENCE();
  __builtin_amdgcn_s_barrier();

  for (int T = 0; T < NT; ++T) {
    const unsigned ab = aBase0 + ((T & 1) ? 32768u : 0u);
    const unsigned bb = bBase0 + ((T & 1) ? 32768u : 0u);

    // ---- q0: issue A(T+1)kh0; read B(8) + A pair 0.
    if (T + 1 < NT) LOAD_A_KH0();
    READ_B8(bb);
    READ_A_PAIR(0, ab);
    SCHED_FENCE();
    __builtin_amdgcn_s_barrier();
    asm volatile("s_waitcnt lgkmcnt(0)");
    SCHED_FENCE();
    __builtin_amdgcn_s_setprio(1);
    MFMA8(0);
    __builtin_amdgcn_s_setprio(0);
    SCHED_FENCE();
    __builtin_amdgcn_s_barrier();

    // ---- q1: A pair 1.
    READ_A_PAIR(1, ab);
    SCHED_FENCE();
    __builtin_amdgcn_s_barrier();
    asm volatile("s_waitcnt lgkmcnt(0)");
    SCHED_FENCE();
    __builtin_amdgcn_s_setprio(1);
    MFMA8(1);
    __builtin_amdgcn_s_setprio(0);
    SCHED_FENCE();
    __builtin_amdgcn_s_barrier();

    // ---- q2: A pair 2; stage B(T+2)h0; vmcnt(2) drains B(T+1)+A(T+1)kh0;
    // write kh0; issue A(T+1)kh1 (ra consumed by cvts first, in-order).
    READ_A_PAIR(2, ab);
    if (T + 2 < NT) {
      STAGE_B_HALF(T + 2, 0);
      SCHED_FENCE();
      asm volatile("s_waitcnt vmcnt(2)");
      SCHED_FENCE();
    } else if (T + 1 < NT) {
      SCHED_FENCE();
      asm volatile("s_waitcnt vmcnt(0)");
      SCHED_FENCE();
    }
    if (T + 1 < NT) {
      WRITE_A_KH(T + 1, 0);
      LOAD_A_KH1();
    }
    SCHED_FENCE();
    __builtin_amdgcn_s_barrier();
    if (T + 1 < NT) {
      asm volatile("s_waitcnt lgkmcnt(4)");   // frag reads done, writes in flight
    } else {
      asm volatile("s_waitcnt lgkmcnt(0)");
    }
    SCHED_FENCE();
    __builtin_amdgcn_s_setprio(1);
    MFMA8(2);
    __builtin_amdgcn_s_setprio(0);
    SCHED_FENCE();
    __builtin_amdgcn_s_barrier();

    // ---- q3: A pair 3; stage B(T+2)h1; vmcnt(2) drains A(T+1)kh1; write kh1.
    READ_A_PAIR(3, ab);
    if (T + 2 < NT) {
      STAGE_B_HALF(T + 2, 1);
      SCHED_FENCE();
      asm volatile("s_waitcnt vmcnt(2)");
      SCHED_FENCE();
    } else if (T + 1 < NT) {
      SCHED_FENCE();
      asm volatile("s_waitcnt vmcnt(0)");
      SCHED_FENCE();
    }
    if (T + 1 < NT) {
      WRITE_A_KH(T + 1, 1);
      ADV_A();
    }
    SCHED_FENCE();
    __builtin_amdgcn_s_barrier();
    if (T + 1 < NT) {
      asm volatile("s_waitcnt lgkmcnt(4)");
    } else {
      asm volatile("s_waitcnt lgkmcnt(0)");
    }
    SCHED_FENCE();
    __builtin_amdgcn_s_setprio(1);
    MFMA8(3);
    __builtin_amdgcn_s_setprio(0);
    asm volatile("s_waitcnt lgkmcnt(0)");
    SCHED_FENCE();
    __builtin_amdgcn_s_barrier();
  }

  // epilogue: C/D layout col = lane&15, row = (lane>>4)*4 + q; scale 1/64
  const int cc = lane & 15;
  const int crr = sl << 2;
#pragma unroll
  for (int ni = 0; ni < 4; ++ni) {
    int col = bn + wc * 64 + ni * 16 + cc;
    float bv = bias[col];
#pragma unroll
    for (int mi = 0; mi < 8; ++mi) {
      int row0 = bm + wr * 128 + mi * 16 + crr;
#pragma unroll
      for (int q = 0; q < 4; ++q)
        F[(size_t)(row0 + q) * DD + col] = f2bf(acc[mi][ni][q] * INV_WSCALE + bv);
    }
  }
#undef READ_B8
#undef READ_A_PAIR
#undef MFMA8
#undef STAGE_B_HALF
#undef LOAD_A_KH0
#undef LOAD_A_KH1
#undef ADV_A
#undef WRITE_A_KH
}

// ---------------------------------------------------------------------------
// Kernel 3: per (batch, t-half): Gram via MFMA -> d2 -> sims -> causal numer
// -> pow/normalize -> out.  (bf16 F input, unchanged)
// ---------------------------------------------------------------------------
__global__ __launch_bounds__(256) void k_batch_sims(const short* __restrict__ F,
                                                    const float* __restrict__ teach,
                                                    const float* __restrict__ cptr,
                                                    const float* __restrict__ gptr,
                                                    float* __restrict__ out) {
  __shared__ short ftile[128][40];
  __shared__ float simsT[64][129];
  __shared__ float sqv[128];
  __shared__ float sqp[256];
  __shared__ float teach_s[128][NC];
  __shared__ float numer[64][NC];
  __shared__ float rsum[64];

  const int b = blockIdx.x >> 1;
  const int half = blockIdx.x & 1;
  const int tid = threadIdx.x;
  const int lane = tid & 63;
  const int w = tid >> 6;
  const size_t fbase = (size_t)b * TT * DD;

  for (int idx = tid; idx < TT * NC; idx += 256)
    teach_s[idx / NC][idx % NC] = teach[(size_t)b * TT * NC + idx];

  {
    int row = tid >> 1;
    int kh = (tid & 1) << 9;
    const short* fp = F + fbase + (size_t)row * DD + kh;
    float s = 0.f;
    for (int k = 0; k < 512; k += 8) {
      short8 v = *reinterpret_cast<const short8*>(fp + k);
#pragma unroll
      for (int j = 0; j < 8; ++j) { float x = bf2f(v[j]); s += x * x; }
    }
    sqp[tid] = s;
  }
  __syncthreads();
  if (tid < 128) sqv[tid] = sqp[2 * tid] + sqp[2 * tid + 1];
  __syncthreads();

  f32x4 acc[2][4] = {};
  const int fr = lane & 15;
  const int fk = (lane >> 4) << 3;
  for (int k0 = 0; k0 < DD; k0 += 32) {
#pragma unroll
    for (int i = 0; i < 2; ++i) {
      int idx = tid + (i << 8);
      int row = idx >> 2;
      int kc = (idx & 3) << 3;
      short8 v = *reinterpret_cast<const short8*>(F + fbase + (size_t)row * DD + (k0 + kc));
      *reinterpret_cast<short8*>(&ftile[row][kc]) = v;
    }
    __syncthreads();
    short8 af[2], bfv[4];
#pragma unroll
    for (int mi = 0; mi < 2; ++mi)
      af[mi] = *reinterpret_cast<const short8*>(&ftile[w * 32 + mi * 16 + fr][fk]);
#pragma unroll
    for (int ni = 0; ni < 4; ++ni)
      bfv[ni] = *reinterpret_cast<const short8*>(&ftile[half * 64 + ni * 16 + fr][fk]);
#pragma unroll
    for (int mi = 0; mi < 2; ++mi)
#pragma unroll
      for (int ni = 0; ni < 4; ++ni)
        acc[mi][ni] = __builtin_amdgcn_mfma_f32_16x16x32_bf16(af[mi], bfv[ni], acc[mi][ni], 0, 0, 0);
    __syncthreads();
  }

  const float c0 = cptr[0];
  const int cc = lane & 15;
  const int crr = (lane >> 4) << 2;
#pragma unroll
  for (int mi = 0; mi < 2; ++mi) {
#pragma unroll
    for (int ni = 0; ni < 4; ++ni) {
#pragma unroll
      for (int q = 0; q < 4; ++q) {
        int s_g = w * 32 + mi * 16 + crr + q;
        int tl = ni * 16 + cc;
        int t_g = half * 64 + tl;
        float g = acc[mi][ni][q];
        float d2 = sqv[s_g] + sqv[t_g] - 2.0f * g;
        d2 = fmaxf(d2, EPS_D2_F);
        float dist = sqrtf(sqrtf(d2));
        simsT[tl][s_g] = (s_g < t_g) ? expf(-c0 * dist) : 0.0f;
      }
    }
  }
  __syncthreads();

  const float gam = gptr[0];
  for (int idx = tid; idx < 64 * NC; idx += 256) {
    int tl = idx / NC, c = idx % NC;
    float s = 0.f;
#pragma unroll 4
    for (int si = 0; si < TT; ++si)
      s += simsT[tl][si] * teach_s[si][c];
    float v = EPS_NUMER_F + s;
    numer[tl][c] = (gam == 1.0f) ? v : powf(v, gam);
  }
  __syncthreads();
  if (tid < 64) {
    float s = 0.f;
#pragma unroll
    for (int c = 0; c < NC; ++c) s += numer[tid][c];
    rsum[tid] = s;
  }
  __syncthreads();
  for (int idx = tid; idx < 64 * NC; idx += 256) {
    int tl = idx / NC, c = idx % NC;
    int t_g = half * 64 + tl;
    float v = numer[tl][c] / rsum[tl];
    if (t_g == 0) v = EPS_NUMER_F;
    out[(size_t)b * TT * NC + (size_t)t_g * NC + c] = v;
  }
}

// ---------------------------------------------------------------------------
extern "C" void kernel_launch(void* const* d_in, const int* in_sizes, int n_in,
                              void* d_out, int out_size, void* d_ws, size_t ws_size,
                              hipStream_t stream) {
  const float* data = (const float*)d_in[1];
  const float* teach = (const float*)d_in[2];
  const float* Wfe = (const float*)d_in[3];
  const float* bfe = (const float*)d_in[4];
  const float* cp = (const float*)d_in[5];
  const float* gp = (const float*)d_in[6];
  float* outp = (float*)d_out;

  char* ws = (char*)d_ws;
  char* Wt8 = ws;                                     // @0:   3.15 MB (fp8)
  short* F = (short*)(ws + (size_t)8 * 1024 * 1024);  // @8MB: 33.55 MB (bf16)

  k_transpose_w8<<<dim3(DD / 32, CHW / 32), 256, 0, stream>>>(Wfe, Wt8);
  k_gemm_mx<<<dim3((MM / 256) * (DD / 256)), 512, 0, stream>>>(data, Wt8, bfe, F);
  k_batch_sims<<<dim3(BB * 2), 256, 0, stream>>>(F, teach, cp, gp, outp);
}